// Round 10
// baseline (347.135 us; speedup 1.0000x reference)
//
#include <hip/hip_runtime.h>

#define IN_SIZE 256
#define N_NODES 1024
#define DEG 32
#define BATCH 16384
#define OUT_SIZE 16
#define COLS 8                        // batch columns per single-wave block
#define N_ROWS (IN_SIZE + N_NODES)    // 1280 activation rows (fp32 in LDS)
#define NPAIR (N_NODES / 2)           // 512 node pairs

// RNE float -> bf16
__device__ __forceinline__ unsigned short f2bf_rne(float f) {
    const unsigned u = __float_as_uint(f);
    return (unsigned short)((u + 0x7FFFu + ((u >> 16) & 1u)) >> 16);
}

// overflow-free tanh: s = e^{-2|z|}, t = sign(z)*(1-s)/(1+s)
__device__ __forceinline__ float tanh6(float z) {
    const float s = __expf(-2.0f * fabsf(z));
    const float r = __builtin_amdgcn_rcpf(1.0f + s);
    return copysignf(fmaf(-s, r, r), z);
}

// butterfly add across lane bits {0,1,2} within 8-aligned groups:
// quad_perm(B1)=xor1, quad_perm(4E)=xor2, row_half_mirror(0x141)=mirror-in-8
// (== xor4 once quads are uniform). Full 8-lane sum in every lane. HW-proven.
template <int CTRL>
__device__ __forceinline__ float dpp_add(float v) {
    return v + __int_as_float(__builtin_amdgcn_mov_dpp(__float_as_int(v), CTRL, 0xF, 0xF, true));
}

// ---------------------------------------------------------------------------
// Runtime dtype detector (unchanged).
// ---------------------------------------------------------------------------
__global__ __launch_bounds__(64) void ne_detect(const void* __restrict__ xraw,
                                                int* __restrict__ flag) {
    const unsigned short* xb = (const unsigned short*)xraw;
    const int tid = threadIdx.x;
    int plausible = 0;
    for (int k = tid; k < 2048; k += 64) {
        const float v = __uint_as_float((unsigned)xb[2 * k] << 16);
        const float a = fabsf(v);
        plausible += (a == 0.0f) || (a > 1e-3f && a < 1e3f) ? 1 : 0;
    }
    for (int off = 32; off > 0; off >>= 1) plausible += __shfl_down(plausible, off);
    if (tid == 0) *flag = (plausible >= (2048 * 9) / 10) ? 1 : 0;
}

// ---------------------------------------------------------------------------
// Packed tables (R9-validated layout) plus the hazard-sparsity flag:
//   pki[P*16 + q*2 + e] = int4  ids[2P+e][4q..4q+3]
//   pkw[P*16 + q*2 + e] = float4 w [2P+e][4q..4q+3]
//   hze4[P*8+q] = {h1,h2,h3,h4} of even node 2P     (replicated over q)
//   hzo4[P*8+q] = {h2,h3,h4,h5} of odd  node 2P+1
//   h1f [P*8+q] = float2 { h1 of odd node, as_float(any-of-9-coeffs-nonzero) }
// h_k(n) = sum_r w[n][r]*[idx[n][r]==256+n-k] (idx>=256 only).
// When the flag is 0 the entire prefold+correction block is an exact no-op
// (fma(0,t,z)==z) -> the hot loop branches around it (wave-uniform scalar).
// ---------------------------------------------------------------------------
__global__ __launch_bounds__(256) void ne_prep(const void* __restrict__ wraw,
                                               const int* __restrict__ idxs,
                                               int4* __restrict__ pki,
                                               float4* __restrict__ pkw,
                                               float4* __restrict__ hze4,
                                               float4* __restrict__ hzo4,
                                               float2* __restrict__ h1f,
                                               const int* __restrict__ flag) {
    const int isbf16 = *flag;                    // uniform
    const int tid = blockIdx.x * 256 + threadIdx.x;
    const int stride = gridDim.x * 256;
    const unsigned short* wb = (const unsigned short*)wraw;
    const float* wsrc = (const float*)wraw;
    for (int k = tid; k < N_NODES * 8; k += stride) {   // k = n*8 + qq
        const int n = k >> 3, qq = k & 7;
        const int e = n * DEG + qq * 4;
        const int dest = (n >> 1) * 16 + qq * 2 + (n & 1);
        pki[dest] = make_int4(idxs[e], idxs[e + 1], idxs[e + 2], idxs[e + 3]);
        float w0 = isbf16 ? __uint_as_float((unsigned)wb[e + 0] << 16) : wsrc[e + 0];
        float w1 = isbf16 ? __uint_as_float((unsigned)wb[e + 1] << 16) : wsrc[e + 1];
        float w2 = isbf16 ? __uint_as_float((unsigned)wb[e + 2] << 16) : wsrc[e + 2];
        float w3 = isbf16 ? __uint_as_float((unsigned)wb[e + 3] << 16) : wsrc[e + 3];
        pkw[dest] = make_float4(w0, w1, w2, w3);
    }
    for (int P = tid; P < NPAIR; P += stride) {
        float he[6] = {0.f, 0.f, 0.f, 0.f, 0.f, 0.f};   // he[d] for even node
        float ho[6] = {0.f, 0.f, 0.f, 0.f, 0.f, 0.f};   // ho[d] for odd node
        for (int e = 0; e < 2; ++e) {
            const int n = 2 * P + e;
            float* hh = e ? ho : he;
            for (int r = 0; r < DEG; ++r) {
                const int id = idxs[n * DEG + r];
                if (id < IN_SIZE) continue;      // input rows are never stale
                const int d = IN_SIZE + n - id;  // id == 256+n-d
                if (d < 1 || d > 5) continue;
                const float w = isbf16 ? __uint_as_float((unsigned)wb[n * DEG + r] << 16)
                                       : wsrc[n * DEG + r];
                hh[d] += w;
            }
        }
        const int nz = (he[1] != 0.f) | (he[2] != 0.f) | (he[3] != 0.f) | (he[4] != 0.f) |
                       (ho[1] != 0.f) | (ho[2] != 0.f) | (ho[3] != 0.f) | (ho[4] != 0.f) |
                       (ho[5] != 0.f);
        const float4 hev = make_float4(he[1], he[2], he[3], he[4]);
        const float4 hov = make_float4(ho[2], ho[3], ho[4], ho[5]);
        const float2 h1v = make_float2(ho[1], __uint_as_float((unsigned)nz));
#pragma unroll
        for (int r = 0; r < 8; ++r) {
            hze4[P * 8 + r] = hev;
            hzo4[P * 8 + r] = hov;
            h1f[P * 8 + r] = h1v;
        }
    }
}

// ---------------------------------------------------------------------------
// COLS=8 pair pipeline (40 KB LDS -> 4 blocks/CU, 1 wave/SIMD, 2 rounds).
// lane = c*8 + q. Per step S: reduce pair S+1; issue gathers pair S+2;
// finalize pair S; refills. NEW: the finalize's prefold+correction block is
// guarded by a wave-uniform scalar branch on the precomputed sparsity flag —
// ~64% of pairs skip it entirely, which (a) removes 9 FMAs of issue and
// (b) BREAKS the cross-pair dependence chain (te/to no longer feed the next
// pair), converting the recurrence into throughput work. Skipped prefolds
// were exact no-ops (fma(0,t,z)) -> bitwise-identical results.
// Single wave => in-order DS => stale reads deterministically 0; no barriers.
// ---------------------------------------------------------------------------
__global__ __launch_bounds__(64) void ne_forward(const void* __restrict__ xraw,
                                                 const int4* __restrict__ pki,
                                                 const float4* __restrict__ pkw,
                                                 const float4* __restrict__ hze4,
                                                 const float4* __restrict__ hzo4,
                                                 const float2* __restrict__ h1f,
                                                 void* __restrict__ outraw,
                                                 const int* __restrict__ flag) {
    __shared__ float act[N_ROWS * COLS];         // 40960 B -> 4 blocks/CU
    const int lane = threadIdx.x;
    const int q = lane & 7;                      // fan-in quad 0..7
    const int c = lane >> 3;                     // batch column 0..7
    const int c0 = blockIdx.x * COLS;
    const int q2 = q * 2;
    const int isbf16 = *flag;                    // uniform
    float* outf = (float*)outraw;
    unsigned short* outb = (unsigned short*)outraw;

    // ---- zero node rows so stale gathers read exactly 0.0 ----
    {
        float4* az = (float4*)(act + IN_SIZE * COLS);   // 2048 float4
#pragma unroll
        for (int t = 0; t < 32; ++t) az[t * 64 + lane] = make_float4(0.f, 0.f, 0.f, 0.f);
    }
    // ---- seed input rows 0..255 from raw x (b = column, seg = 32-elem chunk) ----
    {
        const int b = lane >> 3;
        const int seg = lane & 7;
        if (isbf16) {
            const unsigned short* xb =
                (const unsigned short*)xraw + (size_t)(c0 + b) * IN_SIZE + seg * 32;
#pragma unroll
            for (int t = 0; t < 4; ++t) {
                const uint4 v = *(const uint4*)(xb + t * 8);
                const int k0 = seg * 32 + t * 8;
                act[(k0 + 0) * COLS + b] = __uint_as_float(v.x << 16);
                act[(k0 + 1) * COLS + b] = __uint_as_float(v.x & 0xFFFF0000u);
                act[(k0 + 2) * COLS + b] = __uint_as_float(v.y << 16);
                act[(k0 + 3) * COLS + b] = __uint_as_float(v.y & 0xFFFF0000u);
                act[(k0 + 4) * COLS + b] = __uint_as_float(v.z << 16);
                act[(k0 + 5) * COLS + b] = __uint_as_float(v.z & 0xFFFF0000u);
                act[(k0 + 6) * COLS + b] = __uint_as_float(v.w << 16);
                act[(k0 + 7) * COLS + b] = __uint_as_float(v.w & 0xFFFF0000u);
            }
        } else {
            const float* xs = (const float*)xraw + (size_t)(c0 + b) * IN_SIZE + seg * 32;
#pragma unroll
            for (int t = 0; t < 8; ++t) {
                const float4 v = *(const float4*)(xs + t * 4);
                const int k0 = seg * 32 + t * 4;
                act[(k0 + 0) * COLS + b] = v.x;
                act[(k0 + 1) * COLS + b] = v.y;
                act[(k0 + 2) * COLS + b] = v.z;
                act[(k0 + 3) * COLS + b] = v.w;
            }
        }
    }
    // single wave: in-order DS -> gathers below see the seed; no barrier

    // ---- prologue ----
    float zeA, zoA, zeB, zoB;
    float gE0, gE1, gE2, gE3, gO0, gO1, gO2, gO3;
    {   // pair 0: load, gather, reduce immediately (transient)
        const int4 iE = pki[0 * 16 + q2], iO = pki[0 * 16 + q2 + 1];
        const float4 wE = pkw[0 * 16 + q2], wO = pkw[0 * 16 + q2 + 1];
        float ze = act[iE.x * COLS + c] * wE.x;
        ze = fmaf(act[iE.y * COLS + c], wE.y, ze);
        ze = fmaf(act[iE.z * COLS + c], wE.z, ze);
        ze = fmaf(act[iE.w * COLS + c], wE.w, ze);
        float zo = act[iO.x * COLS + c] * wO.x;
        zo = fmaf(act[iO.y * COLS + c], wO.y, zo);
        zo = fmaf(act[iO.z * COLS + c], wO.z, zo);
        zo = fmaf(act[iO.w * COLS + c], wO.w, zo);
        ze = dpp_add<0xB1>(ze); ze = dpp_add<0x4E>(ze); ze = dpp_add<0x141>(ze);
        zo = dpp_add<0xB1>(zo); zo = dpp_add<0x4E>(zo); zo = dpp_add<0x141>(zo);
        zeA = ze; zoA = zo;
    }
    {   // gathers pair 1 (consumed at step 0's reduce)
        const int4 iE = pki[1 * 16 + q2], iO = pki[1 * 16 + q2 + 1];
        gE0 = act[iE.x * COLS + c]; gE1 = act[iE.y * COLS + c];
        gE2 = act[iE.z * COLS + c]; gE3 = act[iE.w * COLS + c];
        gO0 = act[iO.x * COLS + c]; gO1 = act[iO.y * COLS + c];
        gO2 = act[iO.z * COLS + c]; gO3 = act[iO.w * COLS + c];
    }
    // prime streams: slotA {w(1), ids(2), hz(0)}, slotB {w(2), ids(3), hz(1)}
    int4   idE0 = pki[2 * 16 + q2], idO0 = pki[2 * 16 + q2 + 1];
    int4   idE1 = pki[3 * 16 + q2], idO1 = pki[3 * 16 + q2 + 1];
    float4 wvE0 = pkw[1 * 16 + q2], wvO0 = pkw[1 * 16 + q2 + 1];
    float4 wvE1 = pkw[2 * 16 + q2], wvO1 = pkw[2 * 16 + q2 + 1];
    float4 heA = hze4[0 * 8 + q], hoA = hzo4[0 * 8 + q];
    float4 heB = hze4[1 * 8 + q], hoB = hzo4[1 * 8 + q];
    float2 f1A = h1f[0 * 8 + q],  f1B = h1f[1 * 8 + q];
    float te1 = 0.f, to1 = 0.f, te2 = 0.f, to2 = 0.f;

#define PAIRSTEP(S, IDE, IDO, WVE, WVO, HZE, HZO, H1F, ZEc, ZOc, ZEn, ZOn, OUT, CLAMP) \
    {                                                                                  \
        /* 1) reduce pair S+1 (independent of t-chain) */                              \
        float ze = gE0 * WVE.x; ze = fmaf(gE1, WVE.y, ze);                             \
        ze = fmaf(gE2, WVE.z, ze); ze = fmaf(gE3, WVE.w, ze);                          \
        float zo = gO0 * WVO.x; zo = fmaf(gO1, WVO.y, zo);                             \
        zo = fmaf(gO2, WVO.z, zo); zo = fmaf(gO3, WVO.w, zo);                          \
        ze = dpp_add<0xB1>(ze); ze = dpp_add<0x4E>(ze); ze = dpp_add<0x141>(ze);       \
        zo = dpp_add<0xB1>(zo); zo = dpp_add<0x4E>(zo); zo = dpp_add<0x141>(zo);       \
        ZEn = ze; ZOn = zo;                                                            \
        /* 2) issue gathers pair S+2 (stale pairs S..S+2 covered exactly) */           \
        gE0 = act[IDE.x * COLS + c]; gE1 = act[IDE.y * COLS + c];                      \
        gE2 = act[IDE.z * COLS + c]; gE3 = act[IDE.w * COLS + c];                      \
        gO0 = act[IDO.x * COLS + c]; gO1 = act[IDO.y * COLS + c];                      \
        gO2 = act[IDO.z * COLS + c]; gO3 = act[IDO.w * COLS + c];                      \
        /* 3) finalize pair S: sparsity-gated prefolds (wave-uniform branch) */        \
        float te, to;                                                                  \
        if (__builtin_amdgcn_readfirstlane(__float_as_uint(H1F.y)) != 0) {             \
            float zE = fmaf(HZE.x, to1, ZEc); zE = fmaf(HZE.y, te1, zE);               \
            zE = fmaf(HZE.z, to2, zE); zE = fmaf(HZE.w, te2, zE);                      \
            float zO = fmaf(HZO.x, to1, ZOc); zO = fmaf(HZO.y, te1, zO);               \
            zO = fmaf(HZO.z, to2, zO); zO = fmaf(HZO.w, te2, zO);                      \
            te = tanh6(zE);                                                            \
            zO = fmaf(H1F.x, te, zO);                                                  \
            to = tanh6(zO);                                                            \
        } else {                                                                       \
            te = tanh6(ZEc);                     /* chain broken: independent */       \
            to = tanh6(ZOc);                                                           \
        }                                                                              \
        if (q < 2) {                                                                   \
            act[(IN_SIZE + 2 * (S) + q) * COLS + c] = q ? to : te;                     \
            if (OUT) {                                                                 \
                const size_t o =                                                       \
                    (size_t)(2 * (S) + q - (N_NODES - OUT_SIZE)) * BATCH + c0 + c;     \
                if (isbf16) outb[o] = f2bf_rne(q ? to : te);                           \
                else        outf[o] = q ? to : te;                                     \
            }                                                                          \
        }                                                                              \
        te2 = te1; to2 = to1; te1 = te; to1 = to;                                      \
        /* 4) refills: w(S+3), ids(S+4), hz(S+2) */                                    \
        { const int Pw = (CLAMP) ? (((S) + 3 < NPAIR) ? (S) + 3 : NPAIR - 1) : (S) + 3;\
          const int Pn = (CLAMP) ? (((S) + 4 < NPAIR) ? (S) + 4 : NPAIR - 1) : (S) + 4;\
          const int Ph = (CLAMP) ? (((S) + 2 < NPAIR) ? (S) + 2 : NPAIR - 1) : (S) + 2;\
          WVE = pkw[Pw * 16 + q2]; WVO = pkw[Pw * 16 + q2 + 1];                        \
          IDE = pki[Pn * 16 + q2]; IDO = pki[Pn * 16 + q2 + 1];                        \
          HZE = hze4[Ph * 8 + q]; HZO = hzo4[Ph * 8 + q]; H1F = h1f[Ph * 8 + q]; }     \
    }

    // main loop: pairs 0..503 (nodes 0..1007) — no output, no clamp (S+4 <= 507)
#pragma unroll 1
    for (int S = 0; S < NPAIR - 8; S += 2) {
        PAIRSTEP(S,     idE0, idO0, wvE0, wvO0, heA, hoA, f1A, zeA, zoA, zeB, zoB, 0, 0)
        PAIRSTEP(S + 1, idE1, idO1, wvE1, wvO1, heB, hoB, f1B, zeB, zoB, zeA, zoA, 0, 0)
    }
    // epilogue: pairs 504..511 (nodes 1008..1023 — all outputs)
    {
        const int S = NPAIR - 8;                 // 504 (even -> slot parity holds)
        PAIRSTEP(S + 0, idE0, idO0, wvE0, wvO0, heA, hoA, f1A, zeA, zoA, zeB, zoB, 1, 1)
        PAIRSTEP(S + 1, idE1, idO1, wvE1, wvO1, heB, hoB, f1B, zeB, zoB, zeA, zoA, 1, 1)
        PAIRSTEP(S + 2, idE0, idO0, wvE0, wvO0, heA, hoA, f1A, zeA, zoA, zeB, zoB, 1, 1)
        PAIRSTEP(S + 3, idE1, idO1, wvE1, wvO1, heB, hoB, f1B, zeB, zoB, zeA, zoA, 1, 1)
        PAIRSTEP(S + 4, idE0, idO0, wvE0, wvO0, heA, hoA, f1A, zeA, zoA, zeB, zoB, 1, 1)
        PAIRSTEP(S + 5, idE1, idO1, wvE1, wvO1, heB, hoB, f1B, zeB, zoB, zeA, zoA, 1, 1)
        PAIRSTEP(S + 6, idE0, idO0, wvE0, wvO0, heA, hoA, f1A, zeA, zoA, zeB, zoB, 1, 1)
        PAIRSTEP(S + 7, idE1, idO1, wvE1, wvO1, heB, hoB, f1B, zeB, zoB, zeA, zoA, 1, 1)
    }
#undef PAIRSTEP
}

extern "C" void kernel_launch(void* const* d_in, const int* in_sizes, int n_in,
                              void* d_out, int out_size, void* d_ws, size_t ws_size,
                              hipStream_t stream) {
    const void* x   = d_in[0];                   // [BATCH][IN_SIZE]
    const void* w   = d_in[1];                   // [N_NODES][DEG]
    const int* idxs = (const int*)d_in[2];       // [N_NODES][DEG]

    int4*   pki  = (int4*)d_ws;                                          // 128 KB
    float4* pkw  = (float4*)((char*)d_ws + (size_t)128 * 1024);          // 128 KB
    float4* hze4 = (float4*)((char*)d_ws + (size_t)256 * 1024);          // 64 KB
    float4* hzo4 = (float4*)((char*)d_ws + (size_t)320 * 1024);          // 64 KB
    float2* h1f  = (float2*)((char*)d_ws + (size_t)384 * 1024);          // 32 KB
    int* flag    = (int*)((char*)d_ws + ((ws_size - 16) & ~(size_t)15));

    ne_detect<<<1, 64, 0, stream>>>(x, flag);
    ne_prep<<<32, 256, 0, stream>>>(w, idxs, pki, pkw, hze4, hzo4, h1f, flag);

    // 2048 single-wave blocks, 40 KB LDS -> 4 blocks/CU (1 wave/SIMD),
    // 2 scheduling rounds, zero barriers.
    ne_forward<<<dim3(BATCH / COLS), dim3(64), 0, stream>>>(x, pki, pkw, hze4, hzo4,
                                                            h1f, d_out, flag);
}

// Round 12
// 324.903 us; speedup vs baseline: 1.0684x; 1.0684x over previous
//
#include <hip/hip_runtime.h>

#define IN_SIZE 256
#define N_NODES 1024
#define DEG 32
#define BATCH 16384
#define OUT_SIZE 16
#define COLS 4                        // batch columns per single-wave block
#define N_ROWS (IN_SIZE + N_NODES)    // 1280 activation rows (fp32 in LDS)
#define NPAIR (N_NODES / 2)           // 512 node pairs

// RNE float -> bf16
__device__ __forceinline__ unsigned short f2bf_rne(float f) {
    const unsigned u = __float_as_uint(f);
    return (unsigned short)((u + 0x7FFFu + ((u >> 16) & 1u)) >> 16);
}

// overflow-free tanh: s = e^{-2|z|}, t = sign(z)*(1-s)/(1+s)
__device__ __forceinline__ float tanh6(float z) {
    const float s = __expf(-2.0f * fabsf(z));
    const float r = __builtin_amdgcn_rcpf(1.0f + s);
    return copysignf(fmaf(-s, r, r), z);
}

// butterfly add across lane bits {0,1,2}: quad_perm(B1)=xor1, quad_perm(4E)=xor2,
// row_half_mirror(0x141)=mirror-in-8 (==xor4 once quads uniform). HW-proven.
template <int CTRL>
__device__ __forceinline__ float dpp_add(float v) {
    return v + __int_as_float(__builtin_amdgcn_mov_dpp(__float_as_int(v), CTRL, 0xF, 0xF, true));
}
// cross-half exchange within a 16-lane row: row_ror:8 (HW-proven ctrl 0x128)
__device__ __forceinline__ float dpp_ror8(float v) {
    return __int_as_float(__builtin_amdgcn_mov_dpp(__float_as_int(v), 0x128, 0xF, 0xF, true));
}

// ---------------------------------------------------------------------------
// Runtime dtype detector (unchanged).
// ---------------------------------------------------------------------------
__global__ __launch_bounds__(64) void ne_detect(const void* __restrict__ xraw,
                                                int* __restrict__ flag) {
    const unsigned short* xb = (const unsigned short*)xraw;
    const int tid = threadIdx.x;
    int plausible = 0;
    for (int k = tid; k < 2048; k += 64) {
        const float v = __uint_as_float((unsigned)xb[2 * k] << 16);
        const float a = fabsf(v);
        plausible += (a == 0.0f) || (a > 1e-3f && a < 1e3f) ? 1 : 0;
    }
    for (int off = 32; off > 0; off >>= 1) plausible += __shfl_down(plausible, off);
    if (tid == 0) *flag = (plausible >= (2048 * 9) / 10) ? 1 : 0;
}

// ---------------------------------------------------------------------------
// Packed tables (R8-proven layout, window extended to 7):
//   pki[n*8+qq] = int4 BYTE-scaled ids (id*COLS*4) of node n, quad qq
//   pkw[n*8+qq] = float4 w[n][4qq..]
//   hzA[n*8+qq] = prefold coeffs on (ts1,to1,ts2,to2)   [replicated over qq]
//   hzB[n*8+qq] = {c_ts3, c_to3, hcc, 0}
// h_k(n) = sum_r w[n][r]*[idx[n][r]==256+n-k] (idx>=256 only), k=1..7.
// Gathers for pair Q are issued at step Q-3 BEFORE write(Q-3) -> stale pairs
// Q-3..Q. Per-lane ts/to regs hold self/other-parity t of pairs Q-1..Q-3:
//   even n=2Q: ts1=t_{n-2},to1=t_{n-1},ts2=t_{n-4},to2=t_{n-3},ts3=t_{n-6},
//              to3=t_{n-5} -> hzA={h2,h1,h4,h3}, hzB={h6,h5,0,0}
//   odd n=2Q+1: ts*=to-series -> hzA={h2,h3,h4,h5}, hzB={h6,h7,h1,0}
//   (hcc=h1 applied to ror8(t1)=te in-pair; even hcc=0 -> exact recompute)
// ---------------------------------------------------------------------------
__global__ __launch_bounds__(256) void ne_prep(const void* __restrict__ wraw,
                                               const int* __restrict__ idxs,
                                               int4* __restrict__ pki,
                                               float4* __restrict__ pkw,
                                               float4* __restrict__ hzA,
                                               float4* __restrict__ hzB,
                                               const int* __restrict__ flag) {
    const int isbf16 = *flag;                    // uniform
    const int tid = blockIdx.x * 256 + threadIdx.x;
    const int stride = gridDim.x * 256;
    const unsigned short* wb = (const unsigned short*)wraw;
    const float* wsrc = (const float*)wraw;
    for (int k = tid; k < N_NODES * 8; k += stride) {   // k = n*8 + qq
        const int n = k >> 3, qq = k & 7;
        const int e = n * DEG + qq * 4;
        pki[k] = make_int4(idxs[e] * 16, idxs[e + 1] * 16,
                           idxs[e + 2] * 16, idxs[e + 3] * 16);
        float w0 = isbf16 ? __uint_as_float((unsigned)wb[e + 0] << 16) : wsrc[e + 0];
        float w1 = isbf16 ? __uint_as_float((unsigned)wb[e + 1] << 16) : wsrc[e + 1];
        float w2 = isbf16 ? __uint_as_float((unsigned)wb[e + 2] << 16) : wsrc[e + 2];
        float w3 = isbf16 ? __uint_as_float((unsigned)wb[e + 3] << 16) : wsrc[e + 3];
        pkw[k] = make_float4(w0, w1, w2, w3);
    }
    for (int n = tid; n < N_NODES; n += stride) {
        float h[8] = {0.f, 0.f, 0.f, 0.f, 0.f, 0.f, 0.f, 0.f};
        for (int r = 0; r < DEG; ++r) {
            const int id = idxs[n * DEG + r];
            if (id < IN_SIZE) continue;          // input rows are never stale
            const int d = IN_SIZE + n - id;      // id == 256+n-d
            if (d < 1 || d > 7) continue;
            const float w = isbf16 ? __uint_as_float((unsigned)wb[n * DEG + r] << 16)
                                   : wsrc[n * DEG + r];
            h[d] += w;
        }
        const float4 a = (n & 1) ? make_float4(h[2], h[3], h[4], h[5])
                                 : make_float4(h[2], h[1], h[4], h[3]);
        const float4 b = (n & 1) ? make_float4(h[6], h[7], h[1], 0.f)
                                 : make_float4(h[6], h[5], 0.f, 0.f);
#pragma unroll
        for (int r = 0; r < 8; ++r) { hzA[n * 8 + r] = a; hzB[n * 8 + r] = b; }
    }
}

// ---------------------------------------------------------------------------
// R8-proven decoupled node-pair pipeline (COLS=4, 20 KB LDS -> 8 single-wave
// blocks/CU = 2 waves/SIMD, 2 rounds), gather flight deepened to 2 FULL steps.
// lane = c*16 + h*8 + q (h = lane's node parity, matching pki layout n*8+qq
// indexed as [P*16 + l15]). Step S:
//   1) reduce pair S+1 (4 FMA + 3 DPP; independent of t-chain)
//   2) issue gathers pair S+3 (gap to consume at step S+2 ~ 400cy >> DS lat;
//      stale pairs S..S+3 pre-zeroed, folded back exactly via hzA/hzB)
//   3) finalize pair S: 6 prefold FMA; t1=tanh; z+=hcc*ror8(t1); t=tanh;
//      q==0 lanes write rows 2S,2S+1; roll 6 t-regs
//   4) refills: w(S+3), ids(S+5), hz(S+2) — per-lane dwordx4, vmcnt-only
// Single wave => in-order DS => stale reads deterministically 0; no barriers,
// no branches (R10 lesson).
// ---------------------------------------------------------------------------
__global__ __launch_bounds__(64) void ne_forward(const void* __restrict__ xraw,
                                                 const int4* __restrict__ pki,
                                                 const float4* __restrict__ pkw,
                                                 const float4* __restrict__ hzA,
                                                 const float4* __restrict__ hzB,
                                                 void* __restrict__ outraw,
                                                 const int* __restrict__ flag) {
    __shared__ float act[N_ROWS * COLS];         // 20480 B -> 8 blocks/CU
    const int lane = threadIdx.x;
    const int q = lane & 7;                      // fan-in quad 0..7
    const int h = (lane >> 3) & 1;               // node parity in pair
    const int c = lane >> 4;                     // batch column 0..3
    const int l15 = lane & 15;
    const int c4 = c * 4;                        // byte offset of column
    const int c0 = blockIdx.x * COLS;
    const int isbf16 = *flag;                    // uniform
    const char* actb = (const char*)act;         // byte-addressed gathers
    float* outf = (float*)outraw;
    unsigned short* outb = (unsigned short*)outraw;

    // ---- zero node rows so stale gathers read exactly 0.0 ----
    {
        float4* az = (float4*)(act + IN_SIZE * COLS);   // 1024 float4
#pragma unroll
        for (int t = 0; t < 16; ++t) az[t * 64 + lane] = make_float4(0.f, 0.f, 0.f, 0.f);
    }
    // ---- seed input rows 0..255 from raw x: lane seeds rows l15*16..+15, col c ----
    {
        const int b = c;
        if (isbf16) {
            const unsigned short* xb =
                (const unsigned short*)xraw + (size_t)(c0 + b) * IN_SIZE + l15 * 16;
#pragma unroll
            for (int t = 0; t < 2; ++t) {
                const uint4 v = *(const uint4*)(xb + t * 8);
                const int k0 = l15 * 16 + t * 8;
                act[(k0 + 0) * COLS + b] = __uint_as_float(v.x << 16);
                act[(k0 + 1) * COLS + b] = __uint_as_float(v.x & 0xFFFF0000u);
                act[(k0 + 2) * COLS + b] = __uint_as_float(v.y << 16);
                act[(k0 + 3) * COLS + b] = __uint_as_float(v.y & 0xFFFF0000u);
                act[(k0 + 4) * COLS + b] = __uint_as_float(v.z << 16);
                act[(k0 + 5) * COLS + b] = __uint_as_float(v.z & 0xFFFF0000u);
                act[(k0 + 6) * COLS + b] = __uint_as_float(v.w << 16);
                act[(k0 + 7) * COLS + b] = __uint_as_float(v.w & 0xFFFF0000u);
            }
        } else {
            const float* xs = (const float*)xraw + (size_t)(c0 + b) * IN_SIZE + l15 * 16;
#pragma unroll
            for (int t = 0; t < 4; ++t) {
                const float4 v = *(const float4*)(xs + t * 4);
                const int k0 = l15 * 16 + t * 4;
                act[(k0 + 0) * COLS + b] = v.x;
                act[(k0 + 1) * COLS + b] = v.y;
                act[(k0 + 2) * COLS + b] = v.z;
                act[(k0 + 3) * COLS + b] = v.w;
            }
        }
    }
    // single wave: in-order DS -> gathers below see the seed; no barrier

    // ---- prologue ----
    float accA, accB;
    float gA0, gA1, gA2, gA3, gB0, gB1, gB2, gB3;
    {   // pair 0: gather + reduce immediately (no hazards possible)
        const int4 it = pki[0 * 16 + l15];
        const float4 wt = pkw[0 * 16 + l15];
        float zr =      *(const float*)(actb + (unsigned)(it.x + c4)) * wt.x;
        zr = fmaf(*(const float*)(actb + (unsigned)(it.y + c4)), wt.y, zr);
        zr = fmaf(*(const float*)(actb + (unsigned)(it.z + c4)), wt.z, zr);
        zr = fmaf(*(const float*)(actb + (unsigned)(it.w + c4)), wt.w, zr);
        zr = dpp_add<0xB1>(zr); zr = dpp_add<0x4E>(zr); zr = dpp_add<0x141>(zr);
        accA = zr;
    }
    {   // gathers pair 1 -> gA (consumed step 0), pair 2 -> gB (step 1)
        const int4 i1 = pki[1 * 16 + l15];
        gA0 = *(const float*)(actb + (unsigned)(i1.x + c4));
        gA1 = *(const float*)(actb + (unsigned)(i1.y + c4));
        gA2 = *(const float*)(actb + (unsigned)(i1.z + c4));
        gA3 = *(const float*)(actb + (unsigned)(i1.w + c4));
        const int4 i2 = pki[2 * 16 + l15];
        gB0 = *(const float*)(actb + (unsigned)(i2.x + c4));
        gB1 = *(const float*)(actb + (unsigned)(i2.y + c4));
        gB2 = *(const float*)(actb + (unsigned)(i2.z + c4));
        gB3 = *(const float*)(actb + (unsigned)(i2.w + c4));
    }
    // prime parity slots: slot0 {w(1), ids(3), hz(0)}, slot1 {w(2), ids(4), hz(1)}
    int4   idv0 = pki[3 * 16 + l15], idv1 = pki[4 * 16 + l15];
    float4 wv0  = pkw[1 * 16 + l15], wv1  = pkw[2 * 16 + l15];
    float4 hA0 = hzA[0 * 16 + l15], hB0 = hzB[0 * 16 + l15];
    float4 hA1 = hzA[1 * 16 + l15], hB1 = hzB[1 * 16 + l15];
    float ts1 = 0.f, to1 = 0.f, ts2 = 0.f, to2 = 0.f, ts3 = 0.f, to3 = 0.f;

#define PAIRSTEP(S, GC0, GC1, GC2, GC3, IDV, WVV, HA, HB, ACCc, ACCn, OUT, CLAMP)      \
    {                                                                                  \
        /* 1) reduce pair S+1 (independent of t-chain) */                              \
        float zr = GC0 * WVV.x; zr = fmaf(GC1, WVV.y, zr);                             \
        zr = fmaf(GC2, WVV.z, zr); zr = fmaf(GC3, WVV.w, zr);                          \
        zr = dpp_add<0xB1>(zr); zr = dpp_add<0x4E>(zr); zr = dpp_add<0x141>(zr);       \
        ACCn = zr;                                                                     \
        /* 2) issue gathers pair S+3 (2-step flight; stale pairs S..S+3) */            \
        GC0 = *(const float*)(actb + (unsigned)(IDV.x + c4));                          \
        GC1 = *(const float*)(actb + (unsigned)(IDV.y + c4));                          \
        GC2 = *(const float*)(actb + (unsigned)(IDV.z + c4));                          \
        GC3 = *(const float*)(actb + (unsigned)(IDV.w + c4));                          \
        /* 3) finalize pair S */                                                       \
        float z = fmaf(HA.x, ts1, ACCc);                                               \
        z = fmaf(HA.y, to1, z);                                                        \
        z = fmaf(HA.z, ts2, z);                                                        \
        z = fmaf(HA.w, to2, z);                                                        \
        z = fmaf(HB.x, ts3, z);                                                        \
        z = fmaf(HB.y, to3, z);                                                        \
        const float t1 = tanh6(z);                                                     \
        z = fmaf(HB.z, dpp_ror8(t1), z);         /* even half: HB.z=0 -> no-op */      \
        const float t = tanh6(z);                                                      \
        if (q == 0) {                                                                  \
            act[(IN_SIZE + 2 * (S) + h) * COLS + c] = t;                               \
            if (OUT) {                                                                 \
                const size_t o =                                                       \
                    (size_t)(2 * (S) + h - (N_NODES - OUT_SIZE)) * BATCH + c0 + c;     \
                if (isbf16) outb[o] = f2bf_rne(t); else outf[o] = t;                   \
            }                                                                          \
        }                                                                              \
        ts3 = ts2; to3 = to2; ts2 = ts1; to2 = to1;                                    \
        ts1 = t; to1 = dpp_ror8(t);                                                    \
        /* 4) refills: w(S+3), ids(S+5), hz(S+2) — flight 2 steps each */              \
        { const int Pw = (CLAMP) ? (((S) + 3 < NPAIR) ? (S) + 3 : NPAIR - 1) : (S) + 3;\
          const int Pn = (CLAMP) ? (((S) + 5 < NPAIR) ? (S) + 5 : NPAIR - 1) : (S) + 5;\
          const int Ph = (CLAMP) ? (((S) + 2 < NPAIR) ? (S) + 2 : NPAIR - 1) : (S) + 2;\
          WVV = pkw[(Pw << 4) + l15];                                                  \
          IDV = pki[(Pn << 4) + l15];                                                  \
          HA  = hzA[(Ph << 4) + l15];                                                  \
          HB  = hzB[(Ph << 4) + l15]; }                                                \
    }

    // main loop: pairs 0..503 (nodes 0..1007) — no output, no clamp (S+5 <= 508)
#pragma unroll 1
    for (int S = 0; S < NPAIR - 8; S += 2) {
        PAIRSTEP(S,     gA0, gA1, gA2, gA3, idv0, wv0, hA0, hB0, accA, accB, 0, 0)
        PAIRSTEP(S + 1, gB0, gB1, gB2, gB3, idv1, wv1, hA1, hB1, accB, accA, 0, 0)
    }
    // epilogue: pairs 504..511 (nodes 1008..1023 — all outputs)
    {
        const int S = NPAIR - 8;                 // 504 (even -> slot parity holds)
        PAIRSTEP(S + 0, gA0, gA1, gA2, gA3, idv0, wv0, hA0, hB0, accA, accB, 1, 1)
        PAIRSTEP(S + 1, gB0, gB1, gB2, gB3, idv1, wv1, hA1, hB1, accB, accA, 1, 1)
        PAIRSTEP(S + 2, gA0, gA1, gA2, gA3, idv0, wv0, hA0, hB0, accA, accB, 1, 1)
        PAIRSTEP(S + 3, gB0, gB1, gB2, gB3, idv1, wv1, hA1, hB1, accB, accA, 1, 1)
        PAIRSTEP(S + 4, gA0, gA1, gA2, gA3, idv0, wv0, hA0, hB0, accA, accB, 1, 1)
        PAIRSTEP(S + 5, gB0, gB1, gB2, gB3, idv1, wv1, hA1, hB1, accB, accA, 1, 1)
        PAIRSTEP(S + 6, gA0, gA1, gA2, gA3, idv0, wv0, hA0, hB0, accA, accB, 1, 1)
        PAIRSTEP(S + 7, gB0, gB1, gB2, gB3, idv1, wv1, hA1, hB1, accB, accA, 1, 1)
    }
#undef PAIRSTEP
}

extern "C" void kernel_launch(void* const* d_in, const int* in_sizes, int n_in,
                              void* d_out, int out_size, void* d_ws, size_t ws_size,
                              hipStream_t stream) {
    const void* x   = d_in[0];                   // [BATCH][IN_SIZE]
    const void* w   = d_in[1];                   // [N_NODES][DEG]
    const int* idxs = (const int*)d_in[2];       // [N_NODES][DEG]

    int4*   pki = (int4*)d_ws;                                           // 128 KB
    float4* pkw = (float4*)((char*)d_ws + (size_t)128 * 1024);           // 128 KB
    float4* hzA = (float4*)((char*)d_ws + (size_t)256 * 1024);           // 128 KB
    float4* hzB = (float4*)((char*)d_ws + (size_t)384 * 1024);           // 128 KB
    int* flag   = (int*)((char*)d_ws + ((ws_size - 16) & ~(size_t)15));

    ne_detect<<<1, 64, 0, stream>>>(x, flag);
    ne_prep<<<32, 256, 0, stream>>>(w, idxs, pki, pkw, hzA, hzB, flag);

    // 4096 single-wave blocks, 20 KB LDS -> 8 blocks/CU (2 waves/SIMD),
    // 2 scheduling rounds, zero barriers, zero hot-loop branches.
    ne_forward<<<dim3(BATCH / COLS), dim3(64), 0, stream>>>(x, pki, pkw, hzA, hzB,
                                                            d_out, flag);
}

// Round 13
// 290.174 us; speedup vs baseline: 1.1963x; 1.1197x over previous
//
#include <hip/hip_runtime.h>

#define IN_SIZE 256
#define N_NODES 1024
#define DEG 32
#define BATCH 16384
#define OUT_SIZE 16
#define COLS 4                        // batch columns per single-wave block
#define N_ROWS (IN_SIZE + N_NODES)    // 1280 activation rows (fp32 in LDS)
#define NPAIR (N_NODES / 2)           // 512 node pairs

// RNE float -> bf16
__device__ __forceinline__ unsigned short f2bf_rne(float f) {
    const unsigned u = __float_as_uint(f);
    return (unsigned short)((u + 0x7FFFu + ((u >> 16) & 1u)) >> 16);
}

// overflow-free tanh: s = e^{-2|z|}, t = sign(z)*(1-s)/(1+s)
__device__ __forceinline__ float tanh6(float z) {
    const float s = __expf(-2.0f * fabsf(z));
    const float r = __builtin_amdgcn_rcpf(1.0f + s);
    return copysignf(fmaf(-s, r, r), z);
}

// butterfly add across lane bits {0,1,2}: quad_perm(B1)=xor1, quad_perm(4E)=xor2,
// row_half_mirror(0x141)=mirror-in-8 (==xor4 once quads uniform). HW-proven.
template <int CTRL>
__device__ __forceinline__ float dpp_add(float v) {
    return v + __int_as_float(__builtin_amdgcn_mov_dpp(__float_as_int(v), CTRL, 0xF, 0xF, true));
}
// cross-half exchange within a 16-lane row: row_ror:8 (HW-proven ctrl 0x128)
__device__ __forceinline__ float dpp_ror8(float v) {
    return __int_as_float(__builtin_amdgcn_mov_dpp(__float_as_int(v), 0x128, 0xF, 0xF, true));
}

// ---------------------------------------------------------------------------
// Runtime dtype detector (unchanged).
// ---------------------------------------------------------------------------
__global__ __launch_bounds__(64) void ne_detect(const void* __restrict__ xraw,
                                                int* __restrict__ flag) {
    const unsigned short* xb = (const unsigned short*)xraw;
    const int tid = threadIdx.x;
    int plausible = 0;
    for (int k = tid; k < 2048; k += 64) {
        const float v = __uint_as_float((unsigned)xb[2 * k] << 16);
        const float a = fabsf(v);
        plausible += (a == 0.0f) || (a > 1e-3f && a < 1e3f) ? 1 : 0;
    }
    for (int off = 32; off > 0; off >>= 1) plausible += __shfl_down(plausible, off);
    if (tid == 0) *flag = (plausible >= (2048 * 9) / 10) ? 1 : 0;
}

// ---------------------------------------------------------------------------
// Packed tables (R8-proven, window 5):
//   pki[n*8+qq] = int4 ids[n][4qq..4qq+3]
//   pkw[n*8+qq] = float4 w [n][4qq..4qq+3]
//   hza[n*8+qq] = prefold coeffs on rolling (ts1,to1,ts2,to2) [replicated]
//   hcc[n*8+qq] = in-pair coeff (odd nodes: h1; even: 0)
// Hazard window (gathers for pair Q issued at step Q-2, before write(Q-2)):
// stale pairs Q-2..Q -> even node 2Q needs h1..h4, odd 2Q+1 needs h1..h5:
//   h_k(n) = sum_r w[n][r]*[idx[n][r]==256+n-k], idx>=256 only.
//   even n: hza={h2,h1,h4,h3}, hcc=0.  odd n: hza={h2,h3,h4,h5}, hcc=h1.
// ---------------------------------------------------------------------------
__global__ __launch_bounds__(256) void ne_prep(const void* __restrict__ wraw,
                                               const int* __restrict__ idxs,
                                               int4* __restrict__ pki,
                                               float4* __restrict__ pkw,
                                               float4* __restrict__ hza,
                                               float* __restrict__ hcc,
                                               const int* __restrict__ flag) {
    const int isbf16 = *flag;                    // uniform
    const int tid = blockIdx.x * 256 + threadIdx.x;
    const int stride = gridDim.x * 256;
    const unsigned short* wb = (const unsigned short*)wraw;
    const float* wsrc = (const float*)wraw;
    for (int k = tid; k < N_NODES * 8; k += stride) {   // k = n*8 + qq
        const int n = k >> 3, qq = k & 7;
        const int e = n * DEG + qq * 4;
        pki[k] = make_int4(idxs[e], idxs[e + 1], idxs[e + 2], idxs[e + 3]);
        float w0 = isbf16 ? __uint_as_float((unsigned)wb[e + 0] << 16) : wsrc[e + 0];
        float w1 = isbf16 ? __uint_as_float((unsigned)wb[e + 1] << 16) : wsrc[e + 1];
        float w2 = isbf16 ? __uint_as_float((unsigned)wb[e + 2] << 16) : wsrc[e + 2];
        float w3 = isbf16 ? __uint_as_float((unsigned)wb[e + 3] << 16) : wsrc[e + 3];
        pkw[k] = make_float4(w0, w1, w2, w3);
    }
    for (int n = tid; n < N_NODES; n += stride) {
        float h1 = 0.f, h2 = 0.f, h3 = 0.f, h4 = 0.f, h5 = 0.f;
        for (int r = 0; r < DEG; ++r) {
            const int id = idxs[n * DEG + r];
            if (id < IN_SIZE) continue;          // input rows are never stale
            const int d = IN_SIZE + n - id;      // id == 256+n-d
            if (d < 1 || d > 5) continue;
            const float w = isbf16 ? __uint_as_float((unsigned)wb[n * DEG + r] << 16)
                                   : wsrc[n * DEG + r];
            if (d == 1) h1 += w; else if (d == 2) h2 += w; else if (d == 3) h3 += w;
            else if (d == 4) h4 += w; else h5 += w;
        }
        const float4 a = (n & 1) ? make_float4(h2, h3, h4, h5)
                                 : make_float4(h2, h1, h4, h3);
        const float hc = (n & 1) ? h1 : 0.0f;
#pragma unroll
        for (int r = 0; r < 8; ++r) { hza[n * 8 + r] = a; hcc[n * 8 + r] = hc; }
    }
}

// ---------------------------------------------------------------------------
// R8-proven decoupled node-pair pipeline (COLS=4, 20 KB LDS -> 8 single-wave
// blocks/CU = 2 waves/SIMD, 2 rounds). lane = c*16 + h*8 + q. Step S:
//   1) reduce pair S+1 (4 FMA + 3 DPP; independent of t-chain)
//   2) issue gathers pair S+2 into the OTHER gather set (consumed next step;
//      stale pairs S..S+2 pre-zeroed, folded back exactly via hza/hcc)
//   3) finalize pair S: 4 prefold FMA ordered LATE-OPERAND-LAST (ts2/to2
//      first, ts1/to1 last -> recurrence = 2 FMA + 2 tanh); t1=tanh;
//      z+=hcc*ror8(t1); t=tanh; q==0 lanes write rows 2S,2S+1
//   4) refills: w(S+3), ids(S+4), hz(S+2) — per-lane dwordx4, vmcnt-only
// t-registers use alternating-set RENAME (step parity selects which pair of
// regs is S-1 vs S-2; each step overwrites the S-2 set) -> zero roll moves.
// Single wave => in-order DS => stale reads deterministically 0; no barriers,
// no branches, float-indexed LDS only (R12 lesson: no char* LDS casts).
// ---------------------------------------------------------------------------
__global__ __launch_bounds__(64) void ne_forward(const void* __restrict__ xraw,
                                                 const int4* __restrict__ pki,
                                                 const float4* __restrict__ pkw,
                                                 const float4* __restrict__ hza,
                                                 const float* __restrict__ hcc,
                                                 void* __restrict__ outraw,
                                                 const int* __restrict__ flag) {
    __shared__ float act[N_ROWS * COLS];         // 20480 B -> 8 blocks/CU
    const int lane = threadIdx.x;
    const int q = lane & 7;                      // fan-in quad 0..7
    const int h = (lane >> 3) & 1;               // node parity in pair
    const int c = lane >> 4;                     // batch column 0..3
    const int l15 = lane & 15;
    const int c0 = blockIdx.x * COLS;
    const int isbf16 = *flag;                    // uniform
    float* outf = (float*)outraw;
    unsigned short* outb = (unsigned short*)outraw;

    // ---- zero node rows so stale gathers read exactly 0.0 ----
    {
        float4* az = (float4*)(act + IN_SIZE * COLS);   // 1024 float4
#pragma unroll
        for (int t = 0; t < 16; ++t) az[t * 64 + lane] = make_float4(0.f, 0.f, 0.f, 0.f);
    }
    // ---- seed input rows 0..255 from raw x: lane seeds rows l15*16..+15, col c ----
    {
        const int b = c;
        if (isbf16) {
            const unsigned short* xb =
                (const unsigned short*)xraw + (size_t)(c0 + b) * IN_SIZE + l15 * 16;
#pragma unroll
            for (int t = 0; t < 2; ++t) {
                const uint4 v = *(const uint4*)(xb + t * 8);
                const int k0 = l15 * 16 + t * 8;
                act[(k0 + 0) * COLS + b] = __uint_as_float(v.x << 16);
                act[(k0 + 1) * COLS + b] = __uint_as_float(v.x & 0xFFFF0000u);
                act[(k0 + 2) * COLS + b] = __uint_as_float(v.y << 16);
                act[(k0 + 3) * COLS + b] = __uint_as_float(v.y & 0xFFFF0000u);
                act[(k0 + 4) * COLS + b] = __uint_as_float(v.z << 16);
                act[(k0 + 5) * COLS + b] = __uint_as_float(v.z & 0xFFFF0000u);
                act[(k0 + 6) * COLS + b] = __uint_as_float(v.w << 16);
                act[(k0 + 7) * COLS + b] = __uint_as_float(v.w & 0xFFFF0000u);
            }
        } else {
            const float* xs = (const float*)xraw + (size_t)(c0 + b) * IN_SIZE + l15 * 16;
#pragma unroll
            for (int t = 0; t < 4; ++t) {
                const float4 v = *(const float4*)(xs + t * 4);
                const int k0 = l15 * 16 + t * 4;
                act[(k0 + 0) * COLS + b] = v.x;
                act[(k0 + 1) * COLS + b] = v.y;
                act[(k0 + 2) * COLS + b] = v.z;
                act[(k0 + 3) * COLS + b] = v.w;
            }
        }
    }
    // single wave: in-order DS -> gathers below see the seed; no barrier

    // ---- prologue ----
    float accA, accB;
    float gA0, gA1, gA2, gA3, gB0, gB1, gB2, gB3;
    {   // pair 0: gather + reduce immediately (transient tables)
        const int4 it = pki[(0 << 4) + l15];
        const float4 wt = pkw[(0 << 4) + l15];
        const float x0 = act[it.x * COLS + c], x1 = act[it.y * COLS + c];
        const float x2 = act[it.z * COLS + c], x3 = act[it.w * COLS + c];
        float zr = x0 * wt.x; zr = fmaf(x1, wt.y, zr);
        zr = fmaf(x2, wt.z, zr); zr = fmaf(x3, wt.w, zr);
        zr = dpp_add<0xB1>(zr); zr = dpp_add<0x4E>(zr); zr = dpp_add<0x141>(zr);
        accA = zr;
    }
    {   // gathers pair 1 -> gA (consumed at step 0's reduce)
        const int4 it = pki[(1 << 4) + l15];
        gA0 = act[it.x * COLS + c]; gA1 = act[it.y * COLS + c];
        gA2 = act[it.z * COLS + c]; gA3 = act[it.w * COLS + c];
    }
    int4   idv0 = pki[(2 << 4) + l15], idv1 = pki[(3 << 4) + l15];
    float4 wv0  = pkw[(1 << 4) + l15], wv1  = pkw[(2 << 4) + l15];
    float4 hza0 = hza[(0 << 4) + l15], hza1 = hza[(1 << 4) + l15];
    float  hcc0 = hcc[(0 << 4) + l15], hcc1 = hcc[(1 << 4) + l15];
    // alternating t-register sets (self, other) for pairs S-1 / S-2
    float tE = 0.f, uE = 0.f, tO = 0.f, uO = 0.f;

// Step S. GC* = gathers of pair S+1 (consume), GN* = fill with pair S+2.
// WVV = w(S+1); IDV = ids(S+2); HZA/HCC = pair S coeffs. ACCc->finalize,
// ACCn <- reduce. T1S/T1O = t of pair S-1 (self/other), T2S/T2O = pair S-2
// (read first, then OVERWRITTEN with pair S's t — the rename roll).
#define PAIRSTEP(S, GC0, GC1, GC2, GC3, GN0, GN1, GN2, GN3,                            \
                 IDV, WVV, HZA, HCC, ACCc, ACCn, T1S, T1O, T2S, T2O, OUT, CLAMP)       \
    {                                                                                  \
        /* 1) reduce pair S+1 (independent of t-chain) */                              \
        float zr = GC0 * WVV.x; zr = fmaf(GC1, WVV.y, zr);                             \
        zr = fmaf(GC2, WVV.z, zr); zr = fmaf(GC3, WVV.w, zr);                          \
        zr = dpp_add<0xB1>(zr); zr = dpp_add<0x4E>(zr); zr = dpp_add<0x141>(zr);       \
        ACCn = zr;                                                                     \
        /* 2) issue gathers pair S+2 (stale pairs S..S+2 covered by hza/hcc) */        \
        GN0 = act[IDV.x * COLS + c]; GN1 = act[IDV.y * COLS + c];                      \
        GN2 = act[IDV.z * COLS + c]; GN3 = act[IDV.w * COLS + c];                      \
        /* 3) finalize pair S — late operands (T1*) folded LAST */                     \
        float z = fmaf(HZA.z, T2S, ACCc);                                              \
        z = fmaf(HZA.w, T2O, z);                                                       \
        z = fmaf(HZA.x, T1S, z);                                                       \
        z = fmaf(HZA.y, T1O, z);                                                       \
        const float t1 = tanh6(z);                                                     \
        z = fmaf(HCC, dpp_ror8(t1), z);          /* even: HCC=0 -> unchanged */        \
        const float t = tanh6(z);                                                      \
        if (q == 0) {                                                                  \
            act[(IN_SIZE + 2 * (S) + h) * COLS + c] = t;                               \
            if (OUT) {                                                                 \
                const size_t o =                                                       \
                    (size_t)(2 * (S) + h - (N_NODES - OUT_SIZE)) * BATCH + c0 + c;     \
                if (isbf16) outb[o] = f2bf_rne(t); else outf[o] = t;                   \
            }                                                                          \
        }                                                                              \
        T2S = t; T2O = dpp_ror8(t);              /* rename roll: overwrite S-2 set */  \
        /* 4) refills: w(S+3), ids(S+4), hz(S+2) — flight 2 steps each */              \
        { const int Pw = (CLAMP) ? (((S) + 3 < NPAIR) ? (S) + 3 : NPAIR - 1) : (S) + 3;\
          const int Pn = (CLAMP) ? (((S) + 4 < NPAIR) ? (S) + 4 : NPAIR - 1) : (S) + 4;\
          const int Ph = (CLAMP) ? (((S) + 2 < NPAIR) ? (S) + 2 : NPAIR - 1) : (S) + 2;\
          WVV = pkw[(Pw << 4) + l15];                                                  \
          IDV = pki[(Pn << 4) + l15];                                                  \
          HZA = hza[(Ph << 4) + l15];                                                  \
          HCC = hcc[(Ph << 4) + l15]; }                                                \
    }

    // main loop: pairs 0..503 (nodes 0..1007) — no output, no clamp (S+4 <= 507)
#pragma unroll 1
    for (int S = 0; S < NPAIR - 8; S += 2) {
        PAIRSTEP(S,     gA0, gA1, gA2, gA3, gB0, gB1, gB2, gB3,
                 idv0, wv0, hza0, hcc0, accA, accB, tO, uO, tE, uE, 0, 0)
        PAIRSTEP(S + 1, gB0, gB1, gB2, gB3, gA0, gA1, gA2, gA3,
                 idv1, wv1, hza1, hcc1, accB, accA, tE, uE, tO, uO, 0, 0)
    }
    // epilogue: pairs 504..511 (nodes 1008..1023 — all outputs)
    {
        const int S = NPAIR - 8;                 // 504 (even -> parity holds)
        PAIRSTEP(S + 0, gA0, gA1, gA2, gA3, gB0, gB1, gB2, gB3,
                 idv0, wv0, hza0, hcc0, accA, accB, tO, uO, tE, uE, 1, 1)
        PAIRSTEP(S + 1, gB0, gB1, gB2, gB3, gA0, gA1, gA2, gA3,
                 idv1, wv1, hza1, hcc1, accB, accA, tE, uE, tO, uO, 1, 1)
        PAIRSTEP(S + 2, gA0, gA1, gA2, gA3, gB0, gB1, gB2, gB3,
                 idv0, wv0, hza0, hcc0, accA, accB, tO, uO, tE, uE, 1, 1)
        PAIRSTEP(S + 3, gB0, gB1, gB2, gB3, gA0, gA1, gA2, gA3,
                 idv1, wv1, hza1, hcc1, accB, accA, tE, uE, tO, uO, 1, 1)
        PAIRSTEP(S + 4, gA0, gA1, gA2, gA3, gB0, gB1, gB2, gB3,
                 idv0, wv0, hza0, hcc0, accA, accB, tO, uO, tE, uE, 1, 1)
        PAIRSTEP(S + 5, gB0, gB1, gB2, gB3, gA0, gA1, gA2, gA3,
                 idv1, wv1, hza1, hcc1, accB, accA, tE, uE, tO, uO, 1, 1)
        PAIRSTEP(S + 6, gA0, gA1, gA2, gA3, gB0, gB1, gB2, gB3,
                 idv0, wv0, hza0, hcc0, accA, accB, tO, uO, tE, uE, 1, 1)
        PAIRSTEP(S + 7, gB0, gB1, gB2, gB3, gA0, gA1, gA2, gA3,
                 idv1, wv1, hza1, hcc1, accB, accA, tE, uE, tO, uO, 1, 1)
    }
#undef PAIRSTEP
}

extern "C" void kernel_launch(void* const* d_in, const int* in_sizes, int n_in,
                              void* d_out, int out_size, void* d_ws, size_t ws_size,
                              hipStream_t stream) {
    const void* x   = d_in[0];                   // [BATCH][IN_SIZE]
    const void* w   = d_in[1];                   // [N_NODES][DEG]
    const int* idxs = (const int*)d_in[2];       // [N_NODES][DEG]

    int4*   pki = (int4*)d_ws;                                           // 128 KB
    float4* pkw = (float4*)((char*)d_ws + (size_t)128 * 1024);           // 128 KB
    float4* hza = (float4*)((char*)d_ws + (size_t)256 * 1024);           // 128 KB
    float*  hcc = (float*)((char*)d_ws + (size_t)384 * 1024);            // 32 KB
    int* flag   = (int*)((char*)d_ws + ((ws_size - 16) & ~(size_t)15));

    ne_detect<<<1, 64, 0, stream>>>(x, flag);
    ne_prep<<<32, 256, 0, stream>>>(w, idxs, pki, pkw, hza, hcc, flag);

    // 4096 single-wave blocks, 20 KB LDS -> 8 blocks/CU (2 waves/SIMD),
    // 2 scheduling rounds, zero barriers, zero hot-loop branches.
    ne_forward<<<dim3(BATCH / COLS), dim3(64), 0, stream>>>(x, pki, pkw, hza, hcc,
                                                            d_out, flag);
}